// Round 6
// baseline (85.499 us; speedup 1.0000x reference)
//
#include <hip/hip_runtime.h>
#include <hip/hip_bf16.h>
#include <math.h>

#define BS 8
#define NN 1024
#define FIN 256
#define HEADS 8
#define FO 64
#define NH (HEADS*FO)   /* 512 */
static constexpr float ALPHA = 0.2f;
static constexpr float LOG2E = 1.4426950408889634f;

typedef short bf16x8 __attribute__((ext_vector_type(8)));
typedef float f32x4  __attribute__((ext_vector_type(4)));
typedef unsigned short u16;
typedef unsigned u32;
typedef u16 u16x4v __attribute__((ext_vector_type(4)));
typedef u16 u16x8v __attribute__((ext_vector_type(8)));

__device__ __forceinline__ u16 f2b(float x) {
    __hip_bfloat16 b = __float2bfloat16(x);
    return *reinterpret_cast<u16*>(&b);
}
__device__ __forceinline__ float fexp2(float x) {
#if __has_builtin(__builtin_amdgcn_exp2f)
    return __builtin_amdgcn_exp2f(x);
#else
    float r; asm("v_exp_f32 %0, %1" : "=v"(r) : "v"(x)); return r;
#endif
}
__device__ __forceinline__ void gload_lds16(const void* g, void* l) {
    __builtin_amdgcn_global_load_lds(
        (const __attribute__((address_space(1))) unsigned int*)g,
        (__attribute__((address_space(3))) unsigned int*)l, 16, 0, 0);
}

// ---------------------------------------------------------------------------
// cvt_wT: W[256][512] f32 -> WbT[512][256] bf16, plus WaT[16][256] f32
// ---------------------------------------------------------------------------
__global__ __launch_bounds__(256) void cvt_wT(const float* __restrict__ W,
                                              const float* __restrict__ avec,
                                              u16* __restrict__ WbT,
                                              float* __restrict__ WaT) {
    __shared__ float T[64][65];
    const int hh = blockIdx.x;
    const int n0 = hh * 64, k0 = blockIdx.y * 64;
    const int t = threadIdx.x;
    const int r4 = t >> 6, c = t & 63;
    #pragma unroll
    for (int p = 0; p < 16; ++p) {
        const int r = p * 4 + r4;
        T[r][c] = W[(size_t)(k0 + r) * NH + n0 + c];
    }
    __syncthreads();
    #pragma unroll
    for (int p = 0; p < 16; ++p) {
        const int r = p * 4 + r4;
        WbT[(size_t)(n0 + r) * FIN + k0 + c] = f2b(T[c][r]);
    }
    if (t < 128) {
        const int kl = t & 63, sd = t >> 6;
        float s = 0.f;
        #pragma unroll
        for (int f = 0; f < 64; ++f)
            s += T[kl][f] * avec[hh * 128 + sd * 64 + f];
        WaT[(sd * 8 + hh) * FIN + k0 + kl] = s;
    }
}

// ---------------------------------------------------------------------------
// prep_h: fused h f32->bf16 AND e_src/e_dst = (h @ WaT^T) * log2e (exact f32)
// wave per row; lane c=lane&15 owns attention-column c, kg=lane>>4 k-quarter
// ---------------------------------------------------------------------------
__global__ __launch_bounds__(256) void prep_h(const float* __restrict__ h,
                                              const float* __restrict__ WaT,
                                              u16* __restrict__ hb,
                                              float* __restrict__ esrc,
                                              float* __restrict__ edst) {
    const int t = threadIdx.x, wv = t >> 6, lane = t & 63;
    const int gi = blockIdx.x * 4 + wv;        // b*NN + i
    const float* hr = h + (size_t)gi * FIN;
    {   // bf16 copy: lane covers k = lane*4..+3 (coalesced 16B in / 8B out)
        const float4 v = *reinterpret_cast<const float4*>(hr + lane * 4);
        u16x4v o; o[0]=f2b(v.x); o[1]=f2b(v.y); o[2]=f2b(v.z); o[3]=f2b(v.w);
        *reinterpret_cast<u16x4v*>(hb + (size_t)gi * FIN + lane * 4) = o;
    }
    const int c = lane & 15, kg = lane >> 4;
    const float* hq = hr + kg * 64;
    const float* wr = WaT + (size_t)c * FIN + kg * 64;
    float s = 0.f;
    #pragma unroll
    for (int q = 0; q < 16; ++q) {
        const float4 hv = *reinterpret_cast<const float4*>(hq + q * 4);
        const float4 wv4 = *reinterpret_cast<const float4*>(wr + q * 4);
        s += hv.x*wv4.x + hv.y*wv4.y + hv.z*wv4.z + hv.w*wv4.w;
    }
    s += __shfl_xor(s, 16);
    s += __shfl_xor(s, 32);
    if (lane < 16) {
        const int b = gi >> 10, i = gi & (NN - 1);
        s *= LOG2E;                            // exp2 domain
        if (c < 8) esrc[(size_t)(b * 8 + c) * NN + i] = s;
        else       edst[(size_t)(b * 8 + (c - 8)) * NN + i] = s;
    }
}

// ---------------------------------------------------------------------------
// pack_adj: adjacency -> bitmask, 4 elems/lane (int4) + shuffle-assemble
// ---------------------------------------------------------------------------
__global__ __launch_bounds__(256) void pack_adj(const int* __restrict__ adj,
                                                u32* __restrict__ bits) {
    const int lane = threadIdx.x & 63;
    const size_t e0 = ((size_t)blockIdx.x * 256 + threadIdx.x) * 4;
    const int4 v = *reinterpret_cast<const int4*>(adj + e0);
    u32 x = (v.x ? 1u : 0u) | (v.y ? 2u : 0u) | (v.z ? 4u : 0u) | (v.w ? 8u : 0u);
    {   const u32 r = (u32)__shfl_xor((int)x, 1);
        const int sh = (lane & 1) * 4;  x = (x << sh) | (r << (4 - sh)); }
    {   const u32 r = (u32)__shfl_xor((int)x, 2);
        const int sh = (lane & 2) * 4;  x = (x << sh) | (r << (8 - sh)); }
    {   const u32 r = (u32)__shfl_xor((int)x, 4);
        const int sh = (lane & 4) * 4;  x = (x << sh) | (r << (16 - sh)); }
    if ((lane & 7) == 0) bits[e0 >> 5] = x;
}

// ---------------------------------------------------------------------------
// gemm_whT: Wh = hb @ WbT^T, 64x64 tile, grid 1024 (4 blocks/CU), XCD-chunked.
// ---------------------------------------------------------------------------
__global__ __launch_bounds__(256) void gemm_whT(const u16* __restrict__ hb,
                                                const u16* __restrict__ WbT,
                                                u16* __restrict__ WhT) {
    __shared__ u16 Al[2][64 * 64];
    __shared__ u16 Bl[2][64 * 64];
    const int t = threadIdx.x, wv = t >> 6, lane = t & 63;
    const int g = lane >> 4, l15 = lane & 15;
    const int lid = (blockIdx.x & 7) * 128 + (blockIdx.x >> 3);
    const int m0 = (lid >> 3) * 64;
    const int h  = lid & 7;
    const int lr = lane >> 3;
    const int sch = (lane & 7) ^ lr;

    f32x4 acc[4] = {};

    auto stageA = [&](int buf, int k0) {
        #pragma unroll
        for (int c = 0; c < 2; ++c) {
            const int rowb = wv * 16 + c * 8;
            gload_lds16(hb + (size_t)(m0 + rowb + lr) * FIN + k0 + sch * 8,
                        &Al[buf][rowb * 64]);
        }
    };
    auto stageB = [&](int buf, int k0) {
        #pragma unroll
        for (int c = 0; c < 2; ++c) {
            const int rowb = wv * 16 + c * 8;
            gload_lds16(WbT + (size_t)(h * 64 + rowb + lr) * FIN + k0 + sch * 8,
                        &Bl[buf][rowb * 64]);
        }
    };

    stageA(0, 0); stageB(0, 0);
    __syncthreads();
    for (int kt = 0; kt < 4; ++kt) {
        const int buf = kt & 1;
        if (kt < 3) { stageA(buf ^ 1, (kt + 1) * 64); stageB(buf ^ 1, (kt + 1) * 64); }
        #pragma unroll
        for (int ks = 0; ks < 2; ++ks) {
            const int ch = (ks * 4 + g) ^ (l15 & 7);
            const bf16x8 afr = *reinterpret_cast<const bf16x8*>(
                &Al[buf][(wv * 16 + l15) * 64 + ch * 8]);
            #pragma unroll
            for (int n = 0; n < 4; ++n) {
                const bf16x8 bfr = *reinterpret_cast<const bf16x8*>(
                    &Bl[buf][(n * 16 + l15) * 64 + ch * 8]);
                acc[n] = __builtin_amdgcn_mfma_f32_16x16x32_bf16(afr, bfr, acc[n], 0, 0, 0);
            }
        }
        __syncthreads();
    }

    // epilogue: acc -> LDS scr[64 f][72 i] u16 -> coalesced global stores
    u16* scr = &Al[0][0];                      // 64*72 u16 = 9216 B, fits 16 KB
    #pragma unroll
    for (int n = 0; n < 4; ++n) {
        u16x4v pk;
        #pragma unroll
        for (int r = 0; r < 4; ++r) pk[r] = f2b(acc[n][r]);
        *reinterpret_cast<u16x4v*>(&scr[(n * 16 + l15) * 72 + wv * 16 + g * 4]) = pk;
    }
    __syncthreads();
    const int bh  = (m0 >> 10) * HEADS + h;
    const int il0 = m0 & (NN - 1);
    const int f = t >> 2, q = t & 3;
    const u16x8v v0 = *reinterpret_cast<const u16x8v*>(&scr[f * 72 + q * 16]);
    const u16x8v v1 = *reinterpret_cast<const u16x8v*>(&scr[f * 72 + q * 16 + 8]);
    u16* dst = &WhT[((size_t)bh * 64 + f) * NN + il0 + q * 16];
    *reinterpret_cast<u16x8v*>(dst)     = v0;
    *reinterpret_cast<u16x8v*>(dst + 8) = v1;
}

// ---------------------------------------------------------------------------
// attn_pv: out = softmax(mask(lrelu(e))) @ Wh. 128 threads = 2 waves,
// 32 rows/wave (64-row block) -> B-fragment ds_reads amortized over 2 MFMAs.
// Denominator via mfma(P, ones). grid 1024, XCD-chunked.
// ---------------------------------------------------------------------------
__global__ __launch_bounds__(128) void attn_pv(const u32* __restrict__ bits,
                                               const u16* __restrict__ WhT,
                                               const float* __restrict__ esrc,
                                               const float* __restrict__ edst,
                                               float* __restrict__ out) {
    // LDS bytes: [0,16384) Bs dbuf | [16384,20480) ed f32[1024]
    //            | [20480,28672) bitsT u32[32][64]
    __shared__ u16 lds[(16384 + 4096 + 8192) / 2];
    char* ldsb = (char*)lds;
    u16* Bs = lds;

    const int t = threadIdx.x, wv = t >> 6, lane = t & 63;
    const int g = lane >> 4, l15 = lane & 15;
    const int lr = lane >> 3, sch = (lane & 7) ^ lr;

    // XCD chunk: 128 consecutive lids per XCD (one batch per XCD)
    const int lid = (blockIdx.x & 7) * 128 + (blockIdx.x >> 3);
    const int it = lid & 15, h = (lid >> 4) & 7, b = lid >> 7;
    const int i0 = it * 64;
    const int bh = b * HEADS + h;

    const int r0 = wv * 32 + l15;              // mf=0 row; mf=1 at +16
    const float es0 = esrc[(size_t)bh * NN + i0 + r0];
    const float es1 = esrc[(size_t)bh * NN + i0 + r0 + 16];
    const u16* whb = WhT + (size_t)bh * 64 * NN;

    auto stageB = [&](int buf, int j0) {
        #pragma unroll
        for (int c = 0; c < 4; ++c) {
            const int fb = wv * 32 + c * 8;
            gload_lds16(whb + (size_t)(fb + lr) * NN + j0 + sch * 8,
                        Bs + buf * 4096 + fb * 64);
        }
    };

    {   // one-time: ed row (4 KB) + first V tile
        const float* edr = edst + (size_t)bh * NN;
        gload_lds16(edr + wv * 512 + lane * 4,       ldsb + 16384 + wv * 2048);
        gload_lds16(edr + wv * 512 + 256 + lane * 4, ldsb + 16384 + wv * 2048 + 1024);
        stageB(0, 0);
    }
    {   // bitsT transpose: thread -> row r=t>>1, half=t&1 (16 words)
        const int r = t >> 1, half = t & 1;
        const u32* bsrc = bits + (size_t)(b * NN + i0 + r) * 32 + half * 16;
        int4 w[4];
        #pragma unroll
        for (int k = 0; k < 4; ++k) w[k] = reinterpret_cast<const int4*>(bsrc)[k];
        u32* bt = (u32*)(ldsb + 20480);
        #pragma unroll
        for (int k = 0; k < 4; ++k)
            #pragma unroll
            for (int e = 0; e < 4; ++e)
                bt[(half * 16 + k * 4 + e) * 64 + r] = ((const u32*)&w[k])[e];
    }
    __syncthreads();

    // hoisted per-lane LDS byte bases
    const int bsB[2] = { l15 * 128 + ((0 + g) ^ (l15 & 7)) * 16,
                         l15 * 128 + ((4 + g) ^ (l15 & 7)) * 16 };
    const int edB  = 16384 + g * 32;
    const int btB0 = 20480 + r0 * 4;           // second row group: +64 bytes

    f32x4 acc[2][4] = {};
    f32x4 dsum[2] = {};
    bf16x8 ones;
    #pragma unroll
    for (int q = 0; q < 8; ++q) ones[q] = (short)0x3F80;   // bf16(1.0)

    for (int tt = 0; tt < 16; ++tt) {
        const int buf = tt & 1;
        if (tt < 15) stageB(buf ^ 1, (tt + 1) * 64);
        #pragma unroll
        for (int ks = 0; ks < 2; ++ks) {
            const float4 e0 = *(const float4*)(ldsb + edB + tt * 256 + ks * 128);
            const float4 e1 = *(const float4*)(ldsb + edB + tt * 256 + ks * 128 + 16);
            const u32 w0 = *(const u32*)(ldsb + btB0 + (tt * 2 + ks) * 256);
            const u32 w1 = *(const u32*)(ldsb + btB0 + 64 + (tt * 2 + ks) * 256);
            const u32 by0 = (w0 >> (8 * g)) & 0xffu;
            const u32 by1 = (w1 >> (8 * g)) & 0xffu;
            float ej[8];
            ej[0]=e0.x; ej[1]=e0.y; ej[2]=e0.z; ej[3]=e0.w;
            ej[4]=e1.x; ej[5]=e1.y; ej[6]=e1.z; ej[7]=e1.w;
            float p0[8], p1[8];
            #pragma unroll
            for (int q = 0; q < 8; ++q) {
                float s0 = es0 + ej[q];
                float s1 = es1 + ej[q];
                s0 = fmaxf(s0, ALPHA * s0);                // lrelu (scaled dom)
                s1 = fmaxf(s1, ALPHA * s1);
                s0 = ((by0 >> q) & 1u) ? s0 : -1e30f;      // mask -> exp2 = 0
                s1 = ((by1 >> q) & 1u) ? s1 : -1e30f;
                p0[q] = fexp2(s0);
                p1[q] = fexp2(s1);
            }
            union { u32 u[4]; bf16x8 v; } af0, af1;
            #pragma unroll
            for (int qp = 0; qp < 4; ++qp) {
                af0.u[qp] = ((u32)f2b(p0[2*qp+1]) << 16) | f2b(p0[2*qp]);
                af1.u[qp] = ((u32)f2b(p1[2*qp+1]) << 16) | f2b(p1[2*qp]);
            }
            const char* bsb = ldsb + buf * 8192 + bsB[ks];
            #pragma unroll
            for (int n = 0; n < 4; ++n) {
                const bf16x8 bfr = *(const bf16x8*)(bsb + n * 2048);
                acc[0][n] = __builtin_amdgcn_mfma_f32_16x16x32_bf16(af0.v, bfr, acc[0][n], 0, 0, 0);
                acc[1][n] = __builtin_amdgcn_mfma_f32_16x16x32_bf16(af1.v, bfr, acc[1][n], 0, 0, 0);
            }
            dsum[0] = __builtin_amdgcn_mfma_f32_16x16x32_bf16(af0.v, ones, dsum[0], 0, 0, 0);
            dsum[1] = __builtin_amdgcn_mfma_f32_16x16x32_bf16(af1.v, ones, dsum[1], 0, 0, 0);
        }
        if (tt < 15) __syncthreads();
    }

    #pragma unroll
    for (int mf = 0; mf < 2; ++mf) {
        float inv[4];
        #pragma unroll
        for (int r = 0; r < 4; ++r) inv[r] = 1.0f / dsum[mf][r];
        #pragma unroll
        for (int n = 0; n < 4; ++n)
            #pragma unroll
            for (int r = 0; r < 4; ++r) {
                const int io = i0 + wv * 32 + mf * 16 + g * 4 + r;
                out[(size_t)(b * NN + io) * NH + h * 64 + n * 16 + l15] =
                    acc[mf][n][r] * inv[r];
            }
    }
}

// ---------------------------------------------------------------------------
extern "C" void kernel_launch(void* const* d_in, const int* in_sizes, int n_in,
                              void* d_out, int out_size, void* d_ws, size_t ws_size,
                              hipStream_t stream) {
    const float* h   = (const float*)d_in[0];
    const int*   adj = (const int*)  d_in[1];
    const float* W   = (const float*)d_in[2];
    const float* a   = (const float*)d_in[3];
    float* out = (float*)d_out;

    char* p = (char*)d_ws;
    u16*   hb   = (u16*)p;   p += (size_t)BS * NN * FIN * 2;        // 4 MB
    u16*   WbT  = (u16*)p;   p += (size_t)NH * FIN * 2;             // 256 KB
    u16*   WhT  = (u16*)p;   p += (size_t)BS * HEADS * FO * NN * 2; // 8 MB
    float* WaT  = (float*)p; p += (size_t)16 * FIN * 4;             // 16 KB
    float* esrc = (float*)p; p += (size_t)BS * HEADS * NN * 4;      // 256 KB
    float* edst = (float*)p; p += (size_t)BS * HEADS * NN * 4;      // 256 KB
    u32*   bits = (u32*)p;                                          // 1 MB

    cvt_wT  <<<dim3(HEADS, FIN / 64), 256, 0, stream>>>(W, a, WbT, WaT);
    prep_h  <<<(BS * NN) / 4, 256, 0, stream>>>(h, WaT, hb, esrc, edst);
    pack_adj<<<(BS * NN * NN) / (256 * 4), 256, 0, stream>>>(adj, bits);
    gemm_whT<<<1024, 256, 0, stream>>>(hb, WbT, WhT);
    attn_pv <<<1024, 128, 0, stream>>>(bits, WhT, esrc, edst, out);
}

// Round 7
// 73.601 us; speedup vs baseline: 1.1617x; 1.1617x over previous
//
#include <hip/hip_runtime.h>
#include <hip/hip_bf16.h>
#include <math.h>

#define BS 8
#define NN 1024
#define FIN 256
#define HEADS 8
#define FO 64
#define NH (HEADS*FO)   /* 512 */
static constexpr float ALPHA = 0.2f;
static constexpr float LOG2E = 1.4426950408889634f;

typedef short bf16x8 __attribute__((ext_vector_type(8)));
typedef float f32x4  __attribute__((ext_vector_type(4)));
typedef unsigned short u16;
typedef unsigned u32;
typedef u16 u16x4v __attribute__((ext_vector_type(4)));
typedef u16 u16x8v __attribute__((ext_vector_type(8)));

__device__ __forceinline__ u16 f2b(float x) {
    __hip_bfloat16 b = __float2bfloat16(x);
    return *reinterpret_cast<u16*>(&b);
}
__device__ __forceinline__ float fexp2(float x) {
#if __has_builtin(__builtin_amdgcn_exp2f)
    return __builtin_amdgcn_exp2f(x);
#else
    float r; asm("v_exp_f32 %0, %1" : "=v"(r) : "v"(x)); return r;
#endif
}
__device__ __forceinline__ void gload_lds16(const void* g, void* l) {
    __builtin_amdgcn_global_load_lds(
        (const __attribute__((address_space(1))) unsigned int*)g,
        (__attribute__((address_space(3))) unsigned int*)l, 16, 0, 0);
}

// ---------------------------------------------------------------------------
// cvt_wT: W[256][512] f32 -> WbT[512][256] bf16, plus WaT[16][256] f32
// ---------------------------------------------------------------------------
__global__ __launch_bounds__(256) void cvt_wT(const float* __restrict__ W,
                                              const float* __restrict__ avec,
                                              u16* __restrict__ WbT,
                                              float* __restrict__ WaT) {
    __shared__ float T[64][65];
    const int hh = blockIdx.x;
    const int n0 = hh * 64, k0 = blockIdx.y * 64;
    const int t = threadIdx.x;
    const int r4 = t >> 6, c = t & 63;
    #pragma unroll
    for (int p = 0; p < 16; ++p) {
        const int r = p * 4 + r4;
        T[r][c] = W[(size_t)(k0 + r) * NH + n0 + c];
    }
    __syncthreads();
    #pragma unroll
    for (int p = 0; p < 16; ++p) {
        const int r = p * 4 + r4;
        WbT[(size_t)(n0 + r) * FIN + k0 + c] = f2b(T[c][r]);
    }
    if (t < 128) {
        const int kl = t & 63, sd = t >> 6;
        float s = 0.f;
        #pragma unroll
        for (int f = 0; f < 64; ++f)
            s += T[kl][f] * avec[hh * 128 + sd * 64 + f];
        WaT[(sd * 8 + hh) * FIN + k0 + kl] = s;
    }
}

// ---------------------------------------------------------------------------
// prep_h: fused h f32->bf16 AND e_src/e_dst = (h @ WaT^T) * log2e (exact f32)
// ---------------------------------------------------------------------------
__global__ __launch_bounds__(256) void prep_h(const float* __restrict__ h,
                                              const float* __restrict__ WaT,
                                              u16* __restrict__ hb,
                                              float* __restrict__ esrc,
                                              float* __restrict__ edst) {
    const int t = threadIdx.x, wv = t >> 6, lane = t & 63;
    const int gi = blockIdx.x * 4 + wv;        // b*NN + i
    const float* hr = h + (size_t)gi * FIN;
    {
        const float4 v = *reinterpret_cast<const float4*>(hr + lane * 4);
        u16x4v o; o[0]=f2b(v.x); o[1]=f2b(v.y); o[2]=f2b(v.z); o[3]=f2b(v.w);
        *reinterpret_cast<u16x4v*>(hb + (size_t)gi * FIN + lane * 4) = o;
    }
    const int c = lane & 15, kg = lane >> 4;
    const float* hq = hr + kg * 64;
    const float* wr = WaT + (size_t)c * FIN + kg * 64;
    float s = 0.f;
    #pragma unroll
    for (int q = 0; q < 16; ++q) {
        const float4 hv = *reinterpret_cast<const float4*>(hq + q * 4);
        const float4 wv4 = *reinterpret_cast<const float4*>(wr + q * 4);
        s += hv.x*wv4.x + hv.y*wv4.y + hv.z*wv4.z + hv.w*wv4.w;
    }
    s += __shfl_xor(s, 16);
    s += __shfl_xor(s, 32);
    if (lane < 16) {
        const int b = gi >> 10, i = gi & (NN - 1);
        s *= LOG2E;                            // exp2 domain
        if (c < 8) esrc[(size_t)(b * 8 + c) * NN + i] = s;
        else       edst[(size_t)(b * 8 + (c - 8)) * NN + i] = s;
    }
}

// ---------------------------------------------------------------------------
// pack_adj: adjacency -> bitmask, 4 elems/lane (int4) + shuffle-assemble
// ---------------------------------------------------------------------------
__global__ __launch_bounds__(256) void pack_adj(const int* __restrict__ adj,
                                                u32* __restrict__ bits) {
    const int lane = threadIdx.x & 63;
    const size_t e0 = ((size_t)blockIdx.x * 256 + threadIdx.x) * 4;
    const int4 v = *reinterpret_cast<const int4*>(adj + e0);
    u32 x = (v.x ? 1u : 0u) | (v.y ? 2u : 0u) | (v.z ? 4u : 0u) | (v.w ? 8u : 0u);
    {   const u32 r = (u32)__shfl_xor((int)x, 1);
        const int sh = (lane & 1) * 4;  x = (x << sh) | (r << (4 - sh)); }
    {   const u32 r = (u32)__shfl_xor((int)x, 2);
        const int sh = (lane & 2) * 4;  x = (x << sh) | (r << (8 - sh)); }
    {   const u32 r = (u32)__shfl_xor((int)x, 4);
        const int sh = (lane & 4) * 4;  x = (x << sh) | (r << (16 - sh)); }
    if ((lane & 7) == 0) bits[e0 >> 5] = x;
}

// ---------------------------------------------------------------------------
// gemm_whT: Wh = hb @ WbT^T, 64x64 tile, grid 1024, XCD-chunked.
// ---------------------------------------------------------------------------
__global__ __launch_bounds__(256) void gemm_whT(const u16* __restrict__ hb,
                                                const u16* __restrict__ WbT,
                                                u16* __restrict__ WhT) {
    __shared__ u16 Al[2][64 * 64];
    __shared__ u16 Bl[2][64 * 64];
    const int t = threadIdx.x, wv = t >> 6, lane = t & 63;
    const int g = lane >> 4, l15 = lane & 15;
    const int lid = (blockIdx.x & 7) * 128 + (blockIdx.x >> 3);
    const int m0 = (lid >> 3) * 64;
    const int h  = lid & 7;
    const int lr = lane >> 3;
    const int sch = (lane & 7) ^ lr;

    f32x4 acc[4] = {};

    auto stageA = [&](int buf, int k0) {
        #pragma unroll
        for (int c = 0; c < 2; ++c) {
            const int rowb = wv * 16 + c * 8;
            gload_lds16(hb + (size_t)(m0 + rowb + lr) * FIN + k0 + sch * 8,
                        &Al[buf][rowb * 64]);
        }
    };
    auto stageB = [&](int buf, int k0) {
        #pragma unroll
        for (int c = 0; c < 2; ++c) {
            const int rowb = wv * 16 + c * 8;
            gload_lds16(WbT + (size_t)(h * 64 + rowb + lr) * FIN + k0 + sch * 8,
                        &Bl[buf][rowb * 64]);
        }
    };

    stageA(0, 0); stageB(0, 0);
    __syncthreads();
    for (int kt = 0; kt < 4; ++kt) {
        const int buf = kt & 1;
        if (kt < 3) { stageA(buf ^ 1, (kt + 1) * 64); stageB(buf ^ 1, (kt + 1) * 64); }
        #pragma unroll
        for (int ks = 0; ks < 2; ++ks) {
            const int ch = (ks * 4 + g) ^ (l15 & 7);
            const bf16x8 afr = *reinterpret_cast<const bf16x8*>(
                &Al[buf][(wv * 16 + l15) * 64 + ch * 8]);
            #pragma unroll
            for (int n = 0; n < 4; ++n) {
                const bf16x8 bfr = *reinterpret_cast<const bf16x8*>(
                    &Bl[buf][(n * 16 + l15) * 64 + ch * 8]);
                acc[n] = __builtin_amdgcn_mfma_f32_16x16x32_bf16(afr, bfr, acc[n], 0, 0, 0);
            }
        }
        __syncthreads();
    }

    u16* scr = &Al[0][0];
    #pragma unroll
    for (int n = 0; n < 4; ++n) {
        u16x4v pk;
        #pragma unroll
        for (int r = 0; r < 4; ++r) pk[r] = f2b(acc[n][r]);
        *reinterpret_cast<u16x4v*>(&scr[(n * 16 + l15) * 72 + wv * 16 + g * 4]) = pk;
    }
    __syncthreads();
    const int bh  = (m0 >> 10) * HEADS + h;
    const int il0 = m0 & (NN - 1);
    const int f = t >> 2, q = t & 3;
    const u16x8v v0 = *reinterpret_cast<const u16x8v*>(&scr[f * 72 + q * 16]);
    const u16x8v v1 = *reinterpret_cast<const u16x8v*>(&scr[f * 72 + q * 16 + 8]);
    u16* dst = &WhT[((size_t)bh * 64 + f) * NN + il0 + q * 16];
    *reinterpret_cast<u16x8v*>(dst)     = v0;
    *reinterpret_cast<u16x8v*>(dst + 8) = v1;
}

// ---------------------------------------------------------------------------
// attn_pv: 256 thr / 4 waves / 64 rows (16 per wave), grid 1024, XCD-chunked.
// Register-prefetched ed/bits, early B-frag loads, packed bf16 cvt,
// denominator via mfma(P, ones).
// ---------------------------------------------------------------------------
__global__ __launch_bounds__(256, 4) void attn_pv(const u32* __restrict__ bits,
                                                  const u16* __restrict__ WhT,
                                                  const float* __restrict__ esrc,
                                                  const float* __restrict__ edst,
                                                  float* __restrict__ out) {
    // LDS bytes: [0,16384) Bs dbuf | [16384,20480) ed f32[1024]
    //            | [20480,28672) bitsT u32[32][64]
    __shared__ u16 lds[(16384 + 4096 + 8192) / 2];
    char* ldsb = (char*)lds;
    u16* Bs = lds;

    const int t = threadIdx.x, wv = t >> 6, lane = t & 63;
    const int g = lane >> 4, l15 = lane & 15;
    const int lr = lane >> 3, sch = (lane & 7) ^ lr;

    const int lid = (blockIdx.x & 7) * 128 + (blockIdx.x >> 3);
    const int it = lid & 15, h = (lid >> 4) & 7, b = lid >> 7;
    const int i0 = it * 64;
    const int bh = b * HEADS + h;

    const int rowl = wv * 16 + l15;
    const float es = esrc[(size_t)bh * NN + i0 + rowl];
    const u16* whb = WhT + (size_t)bh * 64 * NN;

    auto stageB = [&](int buf, int j0) {
        #pragma unroll
        for (int c = 0; c < 2; ++c) {
            const int fb = wv * 16 + c * 8;
            gload_lds16(whb + (size_t)(fb + lr) * NN + j0 + sch * 8,
                        Bs + buf * 4096 + fb * 64);
        }
    };

    {   // one-time: ed row (4 KB) + first V tile
        const float* edr = edst + (size_t)bh * NN;
        gload_lds16(edr + wv * 256 + lane * 4, ldsb + 16384 + wv * 1024);
        stageB(0, 0);
    }
    {   // bitsT transpose: thread t -> row r=t>>2, words wg*8..+7
        const int r = t >> 2, wg = t & 3;
        const u32* bsrc = bits + (size_t)(b * NN + i0 + r) * 32 + wg * 8;
        const int4 w0 = *reinterpret_cast<const int4*>(bsrc);
        const int4 w1 = *reinterpret_cast<const int4*>(bsrc + 4);
        u32* bt = (u32*)(ldsb + 20480);
        #pragma unroll
        for (int q = 0; q < 8; ++q) {
            const u32 val = (q < 4) ? ((const u32*)&w0)[q] : ((const u32*)&w1)[q - 4];
            bt[(wg * 8 + q) * 64 + r] = val;
        }
    }
    __syncthreads();

    const int bsB[2] = { l15 * 128 + ((0 + g) ^ (l15 & 7)) * 16,
                         l15 * 128 + ((4 + g) ^ (l15 & 7)) * 16 };
    const int edB = 16384 + g * 32;          // stride 128 B per ks-step
    const int btB = 20480 + rowl * 4;        // stride 256 B per ks-step

    f32x4 acc[4] = {};
    f32x4 dsum = {};
    bf16x8 ones;
    #pragma unroll
    for (int q = 0; q < 8; ++q) ones[q] = (short)0x3F80;   // bf16(1.0)

    // register prefetch of step 0 (ed/bitsT static after staging)
    float4 pe0 = *(const float4*)(ldsb + edB);
    float4 pe1 = *(const float4*)(ldsb + edB + 16);
    u32    pw  = *(const u32*)  (ldsb + btB);

    for (int tt = 0; tt < 16; ++tt) {
        const int buf = tt & 1;
        if (tt < 15) stageB(buf ^ 1, (tt + 1) * 64);
        #pragma unroll
        for (int ks = 0; ks < 2; ++ks) {
            const int s = tt * 2 + ks;
            const float4 e0 = pe0, e1 = pe1;
            const u32 word = pw;
            if (s < 31) {        // prefetch next step (crosses barrier: safe)
                pe0 = *(const float4*)(ldsb + edB + (s + 1) * 128);
                pe1 = *(const float4*)(ldsb + edB + (s + 1) * 128 + 16);
                pw  = *(const u32*)  (ldsb + btB + (s + 1) * 256);
            }
            // B fragments early: ds latency hides under p-gen
            const char* bsb = ldsb + buf * 8192 + bsB[ks];
            const bf16x8 bfr0 = *(const bf16x8*)(bsb);
            const bf16x8 bfr1 = *(const bf16x8*)(bsb + 2048);
            const bf16x8 bfr2 = *(const bf16x8*)(bsb + 4096);
            const bf16x8 bfr3 = *(const bf16x8*)(bsb + 6144);

            const u32 byte_ = (word >> (8 * g)) & 0xffu;
            float ej[8];
            ej[0]=e0.x; ej[1]=e0.y; ej[2]=e0.z; ej[3]=e0.w;
            ej[4]=e1.x; ej[5]=e1.y; ej[6]=e1.z; ej[7]=e1.w;
            float ps[8];
            #pragma unroll
            for (int q = 0; q < 8; ++q) {
                float sv = es + ej[q];
                sv = fmaxf(sv, ALPHA * sv);                // lrelu (scaled dom)
                sv = ((byte_ >> q) & 1u) ? sv : -1e30f;    // mask -> exp2 = 0
                ps[q] = fexp2(sv);
            }
            union { u32 u[4]; bf16x8 v; } af;
            #pragma unroll
            for (int qp = 0; qp < 4; ++qp) {
                union { __hip_bfloat162 b2; u32 w; } cv;
                cv.b2 = __float22bfloat162_rn(make_float2(ps[2*qp], ps[2*qp+1]));
                af.u[qp] = cv.w;
            }
            acc[0] = __builtin_amdgcn_mfma_f32_16x16x32_bf16(af.v, bfr0, acc[0], 0, 0, 0);
            acc[1] = __builtin_amdgcn_mfma_f32_16x16x32_bf16(af.v, bfr1, acc[1], 0, 0, 0);
            acc[2] = __builtin_amdgcn_mfma_f32_16x16x32_bf16(af.v, bfr2, acc[2], 0, 0, 0);
            acc[3] = __builtin_amdgcn_mfma_f32_16x16x32_bf16(af.v, bfr3, acc[3], 0, 0, 0);
            dsum   = __builtin_amdgcn_mfma_f32_16x16x32_bf16(af.v, ones, dsum,   0, 0, 0);
        }
        if (tt < 15) __syncthreads();
    }

    float inv[4];
    #pragma unroll
    for (int r = 0; r < 4; ++r) inv[r] = 1.0f / dsum[r];
    #pragma unroll
    for (int n = 0; n < 4; ++n)
        #pragma unroll
        for (int r = 0; r < 4; ++r) {
            const int io = i0 + wv * 16 + g * 4 + r;
            out[(size_t)(b * NN + io) * NH + h * 64 + n * 16 + l15] =
                acc[n][r] * inv[r];
        }
}

// ---------------------------------------------------------------------------
extern "C" void kernel_launch(void* const* d_in, const int* in_sizes, int n_in,
                              void* d_out, int out_size, void* d_ws, size_t ws_size,
                              hipStream_t stream) {
    const float* h   = (const float*)d_in[0];
    const int*   adj = (const int*)  d_in[1];
    const float* W   = (const float*)d_in[2];
    const float* a   = (const float*)d_in[3];
    float* out = (float*)d_out;

    char* p = (char*)d_ws;
    u16*   hb   = (u16*)p;   p += (size_t)BS * NN * FIN * 2;        // 4 MB
    u16*   WbT  = (u16*)p;   p += (size_t)NH * FIN * 2;             // 256 KB
    u16*   WhT  = (u16*)p;   p += (size_t)BS * HEADS * FO * NN * 2; // 8 MB
    float* WaT  = (float*)p; p += (size_t)16 * FIN * 4;             // 16 KB
    float* esrc = (float*)p; p += (size_t)BS * HEADS * NN * 4;      // 256 KB
    float* edst = (float*)p; p += (size_t)BS * HEADS * NN * 4;      // 256 KB
    u32*   bits = (u32*)p;                                          // 1 MB

    cvt_wT  <<<dim3(HEADS, FIN / 64), 256, 0, stream>>>(W, a, WbT, WaT);
    prep_h  <<<(BS * NN) / 4, 256, 0, stream>>>(h, WaT, hb, esrc, edst);
    pack_adj<<<(BS * NN * NN) / (256 * 4), 256, 0, stream>>>(adj, bits);
    gemm_whT<<<1024, 256, 0, stream>>>(hb, WbT, WhT);
    attn_pv <<<1024, 256, 0, stream>>>(bits, WhT, esrc, edst, out);
}